// Round 11
// baseline (132.921 us; speedup 1.0000x reference)
//
#include <hip/hip_runtime.h>
#include <cstdint>

typedef __attribute__((ext_vector_type(8))) short short8;
typedef __attribute__((ext_vector_type(4))) short short4v;
typedef __attribute__((ext_vector_type(4))) float f32x4;
typedef unsigned short ushort_t;

#define MFMA(a, b, c) __builtin_amdgcn_mfma_f32_16x16x32_bf16(a, b, c, 0, 0, 0)

__device__ __forceinline__ ushort_t f2bf(float f) {
    unsigned u = __float_as_uint(f);
    u += 0x7FFF + ((u >> 16) & 1);      // round-to-nearest-even
    return (ushort_t)(u >> 16);
}

__device__ __forceinline__ void gld_lds16(const ushort_t* g, ushort_t* l) {
    __builtin_amdgcn_global_load_lds(
        (__attribute__((address_space(1))) void*)g,
        (__attribute__((address_space(3))) void*)l, 16, 0, 0);
}

// ---------------------------------------------------------------------------
// Fused prep: [0,432) wtrans qkv | [432,576) wtrans proj | [576,585) bias.
// (x->bf16 conversion is fused into the qkv GEMM's A-staging.)
// Q columns/bias pre-scaled by (1/sqrt(768))*log2(e) so attn can use exp2.
// ---------------------------------------------------------------------------
__global__ __launch_bounds__(256) void prep(
    const float* __restrict__ w_qkv, ushort_t* __restrict__ wqT,
    const float* __restrict__ w_proj, ushort_t* __restrict__ wpT,
    const float* __restrict__ b_qkv, float* __restrict__ bq_p, float scale) {
    __shared__ float t[64][68];
    const int bid = blockIdx.x;
    const int tid = threadIdx.x;

    if (bid < 576) {                        // ---- weight transpose
        const int qkv_mode = bid < 432;
        const int local = qkv_mode ? bid : bid - 432;
        const int nbx = qkv_mode ? 36 : 12;
        const int J = qkv_mode ? 2304 : 768;
        const float* w = qkv_mode ? w_qkv : w_proj;
        ushort_t* out = qkv_mode ? wqT : wpT;
        const int j0 = (local % nbx) * 64;
        const int k0 = (local / nbx) * 64;
        const int K = 768;
        for (int g = tid; g < 1024; g += 256) {
            int r = g >> 4, c4 = g & 15;
            float4 v = *(const float4*)&w[(size_t)(k0 + r) * J + j0 + c4 * 4];
            *(float4*)&t[r][c4 * 4] = v;
        }
        __syncthreads();
        const int jj = tid >> 2, kc = tid & 3;
        const int j = j0 + jj;
        int jp; float s;
        if (qkv_mode) {
            int which = j % 3, hh = j / 192, d = (j % 192) / 3;
            jp = which * 768 + hh * 64 + d;
            s = (which == 0) ? scale : 1.f;
        } else { jp = j; s = 1.f; }
        ushort_t o[16];
        #pragma unroll
        for (int i = 0; i < 16; ++i) o[i] = f2bf(t[kc * 16 + i][jj] * s);
        uint4 v0, v1;
        v0.x = o[0] | (o[1] << 16);  v0.y = o[2] | (o[3] << 16);
        v0.z = o[4] | (o[5] << 16);  v0.w = o[6] | (o[7] << 16);
        v1.x = o[8] | (o[9] << 16);  v1.y = o[10] | (o[11] << 16);
        v1.z = o[12] | (o[13] << 16); v1.w = o[14] | (o[15] << 16);
        *(uint4*)&out[(size_t)jp * K + k0 + kc * 16] = v0;
        *(uint4*)&out[(size_t)jp * K + k0 + kc * 16 + 8] = v1;
        return;
    }
    {                                       // ---- bias permute
        int j = (bid - 576) * 256 + tid;
        if (j < 2304) {
            int which = j % 3, hh = j / 192, d = (j % 192) / 3;
            bq_p[which * 768 + hh * 64 + d] = b_qkv[j] * (which == 0 ? scale : 1.f);
        }
    }
}

// ---------------------------------------------------------------------------
// C[M,N] = A[M,K] @ Bt[N,K]^T + bias  (fp32 acc)
// 128xBN tile, BK=32, 2-phase double-buffered LDS, plain __syncthreads
// (R9-proven sync).  XCD-chunked block swizzle (T1).
// AF32=1: A is f32; converted to bf16 in-register during staging
// (load-early / ds_write-late so f32-load latency hides under MFMA).
// AF32=0: A is bf16, staged via global_load_lds.
// MODE 0: f32 out.  MODE 1: bf16 out; V-region blocks (n0>=1536) write
// transposed directly to Vt[bh][d][n] (fused vtrans).
// ---------------------------------------------------------------------------
template <int MODE, int BN, int AF32>
__global__ __launch_bounds__(256, 4) void gemm_mfma(
    const void* __restrict__ A, const ushort_t* __restrict__ Bt,
    const float* __restrict__ bias, void* __restrict__ Cout,
    ushort_t* __restrict__ Vt, int M, int N, int K) {
    constexpr int WC = BN / 64;          // col-waves: 2 or 1
    constexpr int WR = 4 / WC;           // row-waves: 2 or 4
    constexpr int MT = 128 / WR / 16;    // row frags/wave: 4 or 2
    constexpr int AELEM = 128 * 32;      // 4096
    constexpr int BELEM = BN * 32;

    __shared__ ushort_t As[2 * AELEM];   // 16KB
    __shared__ ushort_t Bs[2 * BELEM];   // 16KB (BN=128) / 8KB (BN=64)

    const int tid = threadIdx.x;
    const int lane = tid & 63;
    const int wv = tid >> 6;
    const int wr = wv / WC, wc = wv % WC;
    const int l15 = lane & 15;
    const int lg = lane >> 4;

    // XCD-chunked swizzle (grids here are multiples of 8 -> bijective)
    const int nx = gridDim.x;
    const int nwg = nx * gridDim.y;
    const int lin = blockIdx.y * nx + blockIdx.x;
    const int w = (lin & 7) * (nwg >> 3) + (lin >> 3);
    const int m0 = (w / nx) * 128;
    const int n0 = (w % nx) * BN;

    // staging: rows of 32 bf16 = 64B = 4 granules of 16B
    const int rbase = tid >> 2;        // 0..63
    const int c4l = tid & 3;
    const int swz8 = (c4l ^ (rbase & 3)) * 8;

    const ushort_t* gAb = (const ushort_t*)A + (size_t)(m0 + rbase) * K + swz8;
    const float*    gAf = (const float*)A + (size_t)(m0 + rbase) * K + swz8;
    const ushort_t* gB = Bt + (size_t)(n0 + rbase) * K + swz8;

    auto stageB = [&](int buf, int k0) {
        ushort_t* lb = Bs + buf * BELEM + tid * 8;
        #pragma unroll
        for (int rr = 0; rr < BN / 64; ++rr)
            gld_lds16(gB + (size_t)rr * 64 * K + k0, lb + rr * 2048);
    };
    auto stageA_lds = [&](int buf, int k0) {
        ushort_t* la = As + buf * AELEM + tid * 8;
        #pragma unroll
        for (int rr = 0; rr < 2; ++rr)
            gld_lds16(gAb + (size_t)rr * 64 * K + k0, la + rr * 2048);
    };

    float4 ar[2][2];                     // reg-staged A (AF32 path)
    auto loadA = [&](int k0) {
        #pragma unroll
        for (int rr = 0; rr < 2; ++rr) {
            const float* p = gAf + (size_t)rr * 64 * K + k0;
            ar[rr][0] = *(const float4*)p;
            ar[rr][1] = *(const float4*)(p + 4);
        }
    };
    auto writeA = [&](int buf) {
        #pragma unroll
        for (int rr = 0; rr < 2; ++rr) {
            uint4 v;
            v.x = f2bf(ar[rr][0].x) | (f2bf(ar[rr][0].y) << 16);
            v.y = f2bf(ar[rr][0].z) | (f2bf(ar[rr][0].w) << 16);
            v.z = f2bf(ar[rr][1].x) | (f2bf(ar[rr][1].y) << 16);
            v.w = f2bf(ar[rr][1].z) | (f2bf(ar[rr][1].w) << 16);
            *(uint4*)(As + buf * AELEM + tid * 8 + rr * 2048) = v;
        }
    };

    f32x4 acc[MT][4];
    #pragma unroll
    for (int i = 0; i < MT; ++i)
        #pragma unroll
        for (int j = 0; j < 4; ++j) acc[i][j] = (f32x4){0.f, 0.f, 0.f, 0.f};

    const int nk = K >> 5;
    stageB(0, 0);
    if (AF32) { loadA(0); writeA(0); } else { stageA_lds(0, 0); }
    __syncthreads();

    int cur = 0;
    for (int t = 0; t < nk; ++t) {
        if (t + 1 < nk) {
            stageB(cur ^ 1, (t + 1) * 32);
            if (AF32) loadA((t + 1) * 32);
            else      stageA_lds(cur ^ 1, (t + 1) * 32);
        }
        const ushort_t* as = As + cur * AELEM;
        const ushort_t* bs = Bs + cur * BELEM;
        short8 af[MT], bfr[4];
        #pragma unroll
        for (int mt = 0; mt < MT; ++mt) {
            int row = wr * (16 * MT) + mt * 16 + l15;
            int gr = lg ^ (row & 3);
            af[mt] = *(const short8*)&as[row * 32 + gr * 8];
        }
        #pragma unroll
        for (int nt = 0; nt < 4; ++nt) {
            int row = wc * 64 + nt * 16 + l15;
            int gr = lg ^ (row & 3);
            bfr[nt] = *(const short8*)&bs[row * 32 + gr * 8];
        }
        #pragma unroll
        for (int mt = 0; mt < MT; ++mt)
            #pragma unroll
            for (int nt = 0; nt < 4; ++nt)
                acc[mt][nt] = MFMA(af[mt], bfr[nt], acc[mt][nt]);
        if (AF32 && t + 1 < nk) writeA(cur ^ 1);   // after MFMA: load latency hidden
        __syncthreads();
        cur ^= 1;
    }

    if (MODE == 1 && n0 >= 1536) {
        // V region: write transposed to Vt[bh][d][n]
        #pragma unroll
        for (int nt = 0; nt < 4; ++nt) {
            int col = n0 + wc * 64 + nt * 16 + l15;
            int dg = col - 1536;
            int hh = dg >> 6, dd = dg & 63;
            float bb = bias[col];
            #pragma unroll
            for (int mt = 0; mt < MT; ++mt) {
                int row0 = m0 + wr * (16 * MT) + mt * 16 + lg * 4;
                int bb_ = row0 >> 10, n = row0 & 1023;
                short4v pv = {(short)f2bf(acc[mt][nt][0] + bb),
                              (short)f2bf(acc[mt][nt][1] + bb),
                              (short)f2bf(acc[mt][nt][2] + bb),
                              (short)f2bf(acc[mt][nt][3] + bb)};
                *(short4v*)&Vt[(size_t)(bb_ * 12 + hh) * 65536 + (size_t)dd * 1024 + n] = pv;
            }
        }
        return;
    }

    #pragma unroll
    for (int nt = 0; nt < 4; ++nt) {
        int col = n0 + wc * 64 + nt * 16 + l15;
        float bb = bias[col];
        #pragma unroll
        for (int mt = 0; mt < MT; ++mt) {
            int row = m0 + wr * (16 * MT) + mt * 16 + lg * 4;
            #pragma unroll
            for (int r = 0; r < 4; ++r) {
                float v = acc[mt][nt][r] + bb;
                if (MODE == 1)
                    ((ushort_t*)Cout)[(size_t)(row + r) * N + col] = f2bf(v);
                else
                    ((float*)Cout)[(size_t)(row + r) * N + col] = v;
            }
        }
    }
}

// ---------------------------------------------------------------------------
// Flash attention, bf16 MFMA.  Block: 64 q-rows x (b,h), 4 waves x 16 q.
// Swapped QK^T keeps softmax lane-local per q.  K/V double-buffered 2-phase.
// XCD-chunked swizzle.  Separate P buffer, plain __syncthreads (R9-proven).
// ---------------------------------------------------------------------------
__global__ __launch_bounds__(256, 3) void attn_mfma(
    const ushort_t* __restrict__ qkv,   // (4096, 2304) planar [Q|K|V] (V unused)
    const ushort_t* __restrict__ Vt,    // (48, 64, 1024)
    ushort_t* __restrict__ outp) {      // (4096, 768)
    __shared__ ushort_t Qs[4096];        // 8KB
    __shared__ ushort_t Ks[2 * 4096];    // 16KB
    __shared__ ushort_t Vs[2 * 4096];    // 16KB
    __shared__ ushort_t Ps[4096];        // 8KB (wave-private 16x64 each)

    const int tid = threadIdx.x;
    const int lane = tid & 63;
    const int wv = tid >> 6;
    const int l15 = lane & 15;
    const int lg = lane >> 4;

    // XCD-chunked swizzle over grid (16, 48): 768 blocks, 96 per XCD
    const int lin = blockIdx.y * 16 + blockIdx.x;
    const int w = (lin & 7) * 96 + (lin >> 3);
    const int bh = w >> 4;
    const int b = bh / 12, h = bh % 12;
    const int q0 = (w & 15) * 64;

    const int rbase = tid >> 3;
    const int c8l = tid & 7;
    const int swz8 = (c8l ^ (rbase & 7)) * 8;

    const ushort_t* gQ = qkv + (size_t)(b * 1024 + q0 + rbase) * 2304 + h * 64 + swz8;
    const ushort_t* gK = qkv + (size_t)(b * 1024 + rbase) * 2304 + 768 + h * 64 + swz8;
    const ushort_t* gV = Vt + (size_t)bh * 65536 + (size_t)rbase * 1024 + swz8;

    auto stageKV = [&](int buf, int kt) {
        gld_lds16(gK + (size_t)(kt * 64) * 2304, Ks + buf * 4096 + tid * 8);
        gld_lds16(gK + (size_t)(kt * 64 + 32) * 2304, Ks + buf * 4096 + 2048 + tid * 8);
        gld_lds16(gV + kt * 64, Vs + buf * 4096 + tid * 8);
        gld_lds16(gV + kt * 64 + 32 * 1024, Vs + buf * 4096 + 2048 + tid * 8);
    };

    gld_lds16(gQ, Qs + tid * 8);
    gld_lds16(gQ + (size_t)32 * 2304, Qs + tid * 8 + 2048);
    stageKV(0, 0);
    __syncthreads();

    short8 bq[2];
    {
        int row = wv * 16 + l15;
        #pragma unroll
        for (int kk = 0; kk < 2; ++kk) {
            int gr = (kk * 4 + lg) ^ (row & 7);
            bq[kk] = *(const short8*)&Qs[row * 64 + gr * 8];
        }
    }

    float m_run = -1e30f, l_run = 0.f;
    f32x4 o[4];
    #pragma unroll
    for (int dt = 0; dt < 4; ++dt) o[dt] = (f32x4){0.f, 0.f, 0.f, 0.f};

    ushort_t* pb = Ps + wv * 1024;   // wave-private 16x64 P

    int cur = 0;
    for (int kt = 0; kt < 16; ++kt) {
        if (kt < 15) stageKV(cur ^ 1, kt + 1);
        const ushort_t* ks = Ks + cur * 4096;
        const ushort_t* vs = Vs + cur * 4096;

        // S^T = K . Q^T   (64 keys x 16 q)
        f32x4 s[4];
        #pragma unroll
        for (int st = 0; st < 4; ++st) {
            int row = st * 16 + l15;
            short8 a0 = *(const short8*)&ks[row * 64 + (((0 + lg) ^ (row & 7)) * 8)];
            short8 a1 = *(const short8*)&ks[row * 64 + (((4 + lg) ^ (row & 7)) * 8)];
            f32x4 z = (f32x4){0.f, 0.f, 0.f, 0.f};
            z = MFMA(a0, bq[0], z);
            z = MFMA(a1, bq[1], z);
            s[st] = z;
        }

        // online softmax (exp2 units), defer-max when growth <= 8
        float mloc = -1e30f;
        #pragma unroll
        for (int st = 0; st < 4; ++st)
            #pragma unroll
            for (int r = 0; r < 4; ++r) mloc = fmaxf(mloc, s[st][r]);
        mloc = fmaxf(mloc, __shfl_xor(mloc, 16));
        mloc = fmaxf(mloc, __shfl_xor(mloc, 32));

        float psum = 0.f;
        if (__all(mloc <= m_run + 8.f)) {
            #pragma unroll
            for (int st = 0; st < 4; ++st)
                #pragma unroll
                for (int r = 0; r < 4; ++r) {
                    float p = __builtin_amdgcn_exp2f(s[st][r] - m_run);
                    s[st][r] = p;
                    psum += p;
                }
            psum += __shfl_xor(psum, 16);
            psum += __shfl_xor(psum, 32);
            l_run += psum;
        } else {
            float mnew = fmaxf(m_run, mloc);
            float corr = __builtin_amdgcn_exp2f(m_run - mnew);
            #pragma unroll
            for (int st = 0; st < 4; ++st)
                #pragma unroll
                for (int r = 0; r < 4; ++r) {
                    float p = __builtin_amdgcn_exp2f(s[st][r] - mnew);
                    s[st][r] = p;
                    psum += p;
                }
            psum += __shfl_xor(psum, 16);
            psum += __shfl_xor(psum, 32);
            l_run = l_run * corr + psum;
            m_run = mnew;
            #pragma unroll
            for (int dt = 0; dt < 4; ++dt)
                #pragma unroll
                for (int r = 0; r < 4; ++r) o[dt][r] *= corr;
        }

        // stage P^T (16 q x 64 keys, bf16, swizzled) in wave-private LDS
        #pragma unroll
        for (int st = 0; st < 4; ++st) {
            int g8 = st * 2 + (lg >> 1);
            int byteoff = l15 * 128 + ((g8 ^ (l15 & 7)) * 16) + (lg & 1) * 8;
            short4v pv = {(short)f2bf(s[st][0]), (short)f2bf(s[st][1]),
                          (short)f2bf(s[st][2]), (short)f2bf(s[st][3])};
            *(short4v*)((char*)pb + byteoff) = pv;
        }

        // O^T += V^T . P^T  (64 d x 16 q)
        #pragma unroll
        for (int kk = 0; kk < 2; ++kk) {
            int grp = (kk * 4 + lg) ^ (l15 & 7);
            short8 bp = *(const short8*)&pb[l15 * 64 + grp * 8];
            #pragma unroll
            for (int dt = 0; dt < 4; ++dt) {
                int row = dt * 16 + l15;
                int ga = (kk * 4 + lg) ^ (row & 7);
                short8 av = *(const short8*)&vs[row * 64 + ga * 8];
                o[dt] = MFMA(av, bp, o[dt]);
            }
        }
        __syncthreads();
        cur ^= 1;
    }

    // epilogue: normalize, transpose via P buffer, coalesced 16B stores
    const float inv = 1.f / l_run;
    #pragma unroll
    for (int dt = 0; dt < 4; ++dt) {
        short4v pv = {(short)f2bf(o[dt][0] * inv), (short)f2bf(o[dt][1] * inv),
                      (short)f2bf(o[dt][2] * inv), (short)f2bf(o[dt][3] * inv)};
        *(short4v*)&pb[l15 * 64 + dt * 16 + lg * 4] = pv;
    }
    #pragma unroll
    for (int pass = 0; pass < 2; ++pass) {
        int idx = pass * 64 + lane;
        int row = idx >> 3, c8 = idx & 7;
        uint4 v = *(const uint4*)&pb[row * 64 + c8 * 8];
        *(uint4*)&outp[(size_t)(b * 1024 + q0 + wv * 16 + row) * 768 + h * 64 + c8 * 8] = v;
    }
}

// ---------------------------------------------------------------------------
extern "C" void kernel_launch(void* const* d_in, const int* in_sizes, int n_in,
                              void* d_out, int out_size, void* d_ws, size_t ws_size,
                              hipStream_t stream) {
    const float* x = (const float*)d_in[0];
    const float* w_qkv = (const float*)d_in[1];
    const float* b_qkv = (const float*)d_in[2];
    const float* w_proj = (const float*)d_in[3];
    const float* b_proj = (const float*)d_in[4];
    float* outp = (float*)d_out;

    char* ws = (char*)d_ws;
    ushort_t* wqT = (ushort_t*)ws;    ws += (size_t)2304 * 768 * 2;
    ushort_t* wpT = (ushort_t*)ws;    ws += (size_t)768 * 768 * 2;
    float* bq_p = (float*)ws;         ws += (size_t)2304 * 4;
    ushort_t* qkv_bf = (ushort_t*)ws; ws += (size_t)4096 * 2304 * 2;
    ushort_t* Vt = (ushort_t*)ws;     ws += (size_t)48 * 64 * 1024 * 2;
    ushort_t* aout = (ushort_t*)ws;

    // 1/sqrt(768) * log2(e): attn uses exp2
    const float scale = 0.036084391824351615f * 1.4426950408889634f;

    prep<<<585, 256, 0, stream>>>(w_qkv, wqT, w_proj, wpT, b_qkv, bq_p, scale);

    gemm_mfma<1, 128, 1><<<dim3(18, 32), 256, 0, stream>>>(
        x, wqT, bq_p, qkv_bf, Vt, 4096, 2304, 768);

    attn_mfma<<<dim3(16, 48), 256, 0, stream>>>(qkv_bf, Vt, aout);

    gemm_mfma<0, 64, 0><<<dim3(12, 32), 256, 0, stream>>>(
        aout, wpT, b_proj, outp, nullptr, 4096, 768, 768);
}

// Round 12
// 82.399 us; speedup vs baseline: 1.6131x; 1.6131x over previous
//
#include <hip/hip_runtime.h>
#include <cstdint>

typedef __attribute__((ext_vector_type(8))) short short8;
typedef __attribute__((ext_vector_type(4))) short short4v;
typedef __attribute__((ext_vector_type(4))) float f32x4;
typedef unsigned short ushort_t;

#define MFMA(a, b, c) __builtin_amdgcn_mfma_f32_16x16x32_bf16(a, b, c, 0, 0, 0)

__device__ __forceinline__ ushort_t f2bf(float f) {
    unsigned u = __float_as_uint(f);
    u += 0x7FFF + ((u >> 16) & 1);      // round-to-nearest-even
    return (ushort_t)(u >> 16);
}

__device__ __forceinline__ void gld_lds16(const ushort_t* g, ushort_t* l) {
    __builtin_amdgcn_global_load_lds(
        (__attribute__((address_space(1))) void*)g,
        (__attribute__((address_space(3))) void*)l, 16, 0, 0);
}

// ---------------------------------------------------------------------------
// Fused prep: [0,1536) cvt x->bf16 | [1536,1968) wtrans qkv | [1968,2112)
// wtrans proj | [2112,2121) bias permute.
// Q columns/bias pre-scaled by (1/sqrt(768))*log2(e) so attn can use exp2.
// ---------------------------------------------------------------------------
__global__ __launch_bounds__(256) void prep(
    const float* __restrict__ x, ushort_t* __restrict__ x_bf,
    const float* __restrict__ w_qkv, ushort_t* __restrict__ wqT,
    const float* __restrict__ w_proj, ushort_t* __restrict__ wpT,
    const float* __restrict__ b_qkv, float* __restrict__ bq_p, float scale) {
    __shared__ float t[64][68];
    const int bid = blockIdx.x;
    const int tid = threadIdx.x;

    if (bid < 1536) {                       // ---- x -> bf16
        int i = (bid * 256 + tid) * 8;
        float4 a = *(const float4*)&x[i];
        float4 b = *(const float4*)&x[i + 4];
        uint4 v;
        v.x = f2bf(a.x) | (f2bf(a.y) << 16);
        v.y = f2bf(a.z) | (f2bf(a.w) << 16);
        v.z = f2bf(b.x) | (f2bf(b.y) << 16);
        v.w = f2bf(b.z) | (f2bf(b.w) << 16);
        *(uint4*)&x_bf[i] = v;
        return;
    }
    if (bid < 2112) {                       // ---- weight transpose
        const int qkv_mode = bid < 1968;
        const int local = qkv_mode ? bid - 1536 : bid - 1968;
        const int nbx = qkv_mode ? 36 : 12;
        const int J = qkv_mode ? 2304 : 768;
        const float* w = qkv_mode ? w_qkv : w_proj;
        ushort_t* out = qkv_mode ? wqT : wpT;
        const int j0 = (local % nbx) * 64;
        const int k0 = (local / nbx) * 64;
        const int K = 768;
        for (int g = tid; g < 1024; g += 256) {
            int r = g >> 4, c4 = g & 15;
            float4 v = *(const float4*)&w[(size_t)(k0 + r) * J + j0 + c4 * 4];
            *(float4*)&t[r][c4 * 4] = v;
        }
        __syncthreads();
        const int jj = tid >> 2, kc = tid & 3;
        const int j = j0 + jj;
        int jp; float s;
        if (qkv_mode) {
            int which = j % 3, hh = j / 192, d = (j % 192) / 3;
            jp = which * 768 + hh * 64 + d;
            s = (which == 0) ? scale : 1.f;
        } else { jp = j; s = 1.f; }
        ushort_t o[16];
        #pragma unroll
        for (int i = 0; i < 16; ++i) o[i] = f2bf(t[kc * 16 + i][jj] * s);
        uint4 v0, v1;
        v0.x = o[0] | (o[1] << 16);  v0.y = o[2] | (o[3] << 16);
        v0.z = o[4] | (o[5] << 16);  v0.w = o[6] | (o[7] << 16);
        v1.x = o[8] | (o[9] << 16);  v1.y = o[10] | (o[11] << 16);
        v1.z = o[12] | (o[13] << 16); v1.w = o[14] | (o[15] << 16);
        *(uint4*)&out[(size_t)jp * K + k0 + kc * 16] = v0;
        *(uint4*)&out[(size_t)jp * K + k0 + kc * 16 + 8] = v1;
        return;
    }
    {                                       // ---- bias permute
        int j = (bid - 2112) * 256 + tid;
        if (j < 2304) {
            int which = j % 3, hh = j / 192, d = (j % 192) / 3;
            bq_p[which * 768 + hh * 64 + d] = b_qkv[j] * (which == 0 ? scale : 1.f);
        }
    }
}

// ---------------------------------------------------------------------------
// C[M,N] = A[M,K] @ Bt[N,K]^T + bias  (bf16 in, fp32 acc)
// 128xBN tile, BK=32, 2-phase double-buffered LDS, 4 blocks/CU (R6-proven).
// XCD-chunked block swizzle (T1): each XCD gets a contiguous run of
// row-major work ids -> A-panel reuse is XCD-L2-local.
// MODE 0: f32 out.  MODE 1: bf16 out; V-region blocks (n0>=1536) write
// transposed directly to Vt[bh][d][n] (fused vtrans).
// ---------------------------------------------------------------------------
template <int MODE, int BN>
__global__ __launch_bounds__(256, 4) void gemm_mfma(
    const ushort_t* __restrict__ A, const ushort_t* __restrict__ Bt,
    const float* __restrict__ bias, void* __restrict__ Cout,
    ushort_t* __restrict__ Vt, int M, int N, int K) {
    constexpr int WC = BN / 64;          // col-waves: 2 or 1
    constexpr int WR = 4 / WC;           // row-waves: 2 or 4
    constexpr int MT = 128 / WR / 16;    // row frags/wave: 4 or 2
    constexpr int AELEM = 128 * 32;      // 4096
    constexpr int BELEM = BN * 32;

    __shared__ ushort_t As[2 * AELEM];   // 16KB
    __shared__ ushort_t Bs[2 * BELEM];   // 16KB (BN=128) / 8KB (BN=64)

    const int tid = threadIdx.x;
    const int lane = tid & 63;
    const int wv = tid >> 6;
    const int wr = wv / WC, wc = wv % WC;
    const int l15 = lane & 15;
    const int lg = lane >> 4;

    // XCD-chunked swizzle (grids here are multiples of 8 -> bijective)
    const int nx = gridDim.x;
    const int nwg = nx * gridDim.y;
    const int lin = blockIdx.y * nx + blockIdx.x;
    const int w = (lin & 7) * (nwg >> 3) + (lin >> 3);
    const int m0 = (w / nx) * 128;
    const int n0 = (w % nx) * BN;

    // staging: rows of 32 bf16 = 64B = 4 granules of 16B
    const int rbase = tid >> 2;        // 0..63
    const int c4l = tid & 3;
    const int swz8 = (c4l ^ (rbase & 3)) * 8;

    const ushort_t* gA = A + (size_t)(m0 + rbase) * K + swz8;
    const ushort_t* gB = Bt + (size_t)(n0 + rbase) * K + swz8;

    auto stage = [&](int buf, int k0) {
        ushort_t* la = As + buf * AELEM + tid * 8;
        ushort_t* lb = Bs + buf * BELEM + tid * 8;
        #pragma unroll
        for (int rr = 0; rr < 2; ++rr)
            gld_lds16(gA + (size_t)rr * 64 * K + k0, la + rr * 2048);
        #pragma unroll
        for (int rr = 0; rr < BN / 64; ++rr)
            gld_lds16(gB + (size_t)rr * 64 * K + k0, lb + rr * 2048);
    };

    f32x4 acc[MT][4];
    #pragma unroll
    for (int i = 0; i < MT; ++i)
        #pragma unroll
        for (int j = 0; j < 4; ++j) acc[i][j] = (f32x4){0.f, 0.f, 0.f, 0.f};

    const int nk = K >> 5;
    stage(0, 0);
    __syncthreads();

    int cur = 0;
    for (int t = 0; t < nk; ++t) {
        if (t + 1 < nk) stage(cur ^ 1, (t + 1) * 32);
        const ushort_t* as = As + cur * AELEM;
        const ushort_t* bs = Bs + cur * BELEM;
        short8 af[MT], bfr[4];
        #pragma unroll
        for (int mt = 0; mt < MT; ++mt) {
            int row = wr * (16 * MT) + mt * 16 + l15;
            int gr = lg ^ (row & 3);
            af[mt] = *(const short8*)&as[row * 32 + gr * 8];
        }
        #pragma unroll
        for (int nt = 0; nt < 4; ++nt) {
            int row = wc * 64 + nt * 16 + l15;
            int gr = lg ^ (row & 3);
            bfr[nt] = *(const short8*)&bs[row * 32 + gr * 8];
        }
        #pragma unroll
        for (int mt = 0; mt < MT; ++mt)
            #pragma unroll
            for (int nt = 0; nt < 4; ++nt)
                acc[mt][nt] = MFMA(af[mt], bfr[nt], acc[mt][nt]);
        __syncthreads();
        cur ^= 1;
    }

    if (MODE == 1 && n0 >= 1536) {
        // V region: write transposed to Vt[bh][d][n]
        #pragma unroll
        for (int nt = 0; nt < 4; ++nt) {
            int col = n0 + wc * 64 + nt * 16 + l15;
            int dg = col - 1536;
            int hh = dg >> 6, dd = dg & 63;
            float bb = bias[col];
            #pragma unroll
            for (int mt = 0; mt < MT; ++mt) {
                int row0 = m0 + wr * (16 * MT) + mt * 16 + lg * 4;
                int bb_ = row0 >> 10, n = row0 & 1023;
                short4v pv = {(short)f2bf(acc[mt][nt][0] + bb),
                              (short)f2bf(acc[mt][nt][1] + bb),
                              (short)f2bf(acc[mt][nt][2] + bb),
                              (short)f2bf(acc[mt][nt][3] + bb)};
                *(short4v*)&Vt[(size_t)(bb_ * 12 + hh) * 65536 + (size_t)dd * 1024 + n] = pv;
            }
        }
        return;
    }

    #pragma unroll
    for (int nt = 0; nt < 4; ++nt) {
        int col = n0 + wc * 64 + nt * 16 + l15;
        float bb = bias[col];
        #pragma unroll
        for (int mt = 0; mt < MT; ++mt) {
            int row = m0 + wr * (16 * MT) + mt * 16 + lg * 4;
            #pragma unroll
            for (int r = 0; r < 4; ++r) {
                float v = acc[mt][nt][r] + bb;
                if (MODE == 1)
                    ((ushort_t*)Cout)[(size_t)(row + r) * N + col] = f2bf(v);
                else
                    ((float*)Cout)[(size_t)(row + r) * N + col] = v;
            }
        }
    }
}

// ---------------------------------------------------------------------------
// Flash attention, bf16 MFMA.  Block: 64 q-rows x (b,h), 4 waves x 16 q.
// Swapped QK^T keeps softmax lane-local per q.  K/V double-buffered 2-phase.
// XCD-chunked swizzle: 6 whole (b,h) groups per XCD -> K/V L2-local.
// Separate P buffer, plain __syncthreads: replay-safe (R6-proven).
// ---------------------------------------------------------------------------
__global__ __launch_bounds__(256, 3) void attn_mfma(
    const ushort_t* __restrict__ qkv,   // (4096, 2304) planar [Q|K|V] (V unused)
    const ushort_t* __restrict__ Vt,    // (48, 64, 1024)
    ushort_t* __restrict__ outp) {      // (4096, 768)
    __shared__ ushort_t Qs[4096];        // 8KB
    __shared__ ushort_t Ks[2 * 4096];    // 16KB
    __shared__ ushort_t Vs[2 * 4096];    // 16KB
    __shared__ ushort_t Ps[4096];        // 8KB (wave-private 16x64 each)

    const int tid = threadIdx.x;
    const int lane = tid & 63;
    const int wv = tid >> 6;
    const int l15 = lane & 15;
    const int lg = lane >> 4;

    // XCD-chunked swizzle over grid (16, 48): 768 blocks, 96 per XCD
    const int lin = blockIdx.y * 16 + blockIdx.x;
    const int w = (lin & 7) * 96 + (lin >> 3);
    const int bh = w >> 4;
    const int b = bh / 12, h = bh % 12;
    const int q0 = (w & 15) * 64;

    const int rbase = tid >> 3;
    const int c8l = tid & 7;
    const int swz8 = (c8l ^ (rbase & 7)) * 8;

    const ushort_t* gQ = qkv + (size_t)(b * 1024 + q0 + rbase) * 2304 + h * 64 + swz8;
    const ushort_t* gK = qkv + (size_t)(b * 1024 + rbase) * 2304 + 768 + h * 64 + swz8;
    const ushort_t* gV = Vt + (size_t)bh * 65536 + (size_t)rbase * 1024 + swz8;

    auto stageKV = [&](int buf, int kt) {
        gld_lds16(gK + (size_t)(kt * 64) * 2304, Ks + buf * 4096 + tid * 8);
        gld_lds16(gK + (size_t)(kt * 64 + 32) * 2304, Ks + buf * 4096 + 2048 + tid * 8);
        gld_lds16(gV + kt * 64, Vs + buf * 4096 + tid * 8);
        gld_lds16(gV + kt * 64 + 32 * 1024, Vs + buf * 4096 + 2048 + tid * 8);
    };

    gld_lds16(gQ, Qs + tid * 8);
    gld_lds16(gQ + (size_t)32 * 2304, Qs + tid * 8 + 2048);
    stageKV(0, 0);
    __syncthreads();

    short8 bq[2];
    {
        int row = wv * 16 + l15;
        #pragma unroll
        for (int kk = 0; kk < 2; ++kk) {
            int gr = (kk * 4 + lg) ^ (row & 7);
            bq[kk] = *(const short8*)&Qs[row * 64 + gr * 8];
        }
    }

    float m_run = -1e30f, l_run = 0.f;
    f32x4 o[4];
    #pragma unroll
    for (int dt = 0; dt < 4; ++dt) o[dt] = (f32x4){0.f, 0.f, 0.f, 0.f};

    ushort_t* pb = Ps + wv * 1024;   // wave-private 16x64 P

    int cur = 0;
    for (int kt = 0; kt < 16; ++kt) {
        if (kt < 15) stageKV(cur ^ 1, kt + 1);
        const ushort_t* ks = Ks + cur * 4096;
        const ushort_t* vs = Vs + cur * 4096;

        // S^T = K . Q^T   (64 keys x 16 q)
        f32x4 s[4];
        #pragma unroll
        for (int st = 0; st < 4; ++st) {
            int row = st * 16 + l15;
            short8 a0 = *(const short8*)&ks[row * 64 + (((0 + lg) ^ (row & 7)) * 8)];
            short8 a1 = *(const short8*)&ks[row * 64 + (((4 + lg) ^ (row & 7)) * 8)];
            f32x4 z = (f32x4){0.f, 0.f, 0.f, 0.f};
            z = MFMA(a0, bq[0], z);
            z = MFMA(a1, bq[1], z);
            s[st] = z;
        }

        // online softmax (exp2 units), defer-max when growth <= 8
        float mloc = -1e30f;
        #pragma unroll
        for (int st = 0; st < 4; ++st)
            #pragma unroll
            for (int r = 0; r < 4; ++r) mloc = fmaxf(mloc, s[st][r]);
        mloc = fmaxf(mloc, __shfl_xor(mloc, 16));
        mloc = fmaxf(mloc, __shfl_xor(mloc, 32));

        float psum = 0.f;
        if (__all(mloc <= m_run + 8.f)) {
            #pragma unroll
            for (int st = 0; st < 4; ++st)
                #pragma unroll
                for (int r = 0; r < 4; ++r) {
                    float p = __builtin_amdgcn_exp2f(s[st][r] - m_run);
                    s[st][r] = p;
                    psum += p;
                }
            psum += __shfl_xor(psum, 16);
            psum += __shfl_xor(psum, 32);
            l_run += psum;
        } else {
            float mnew = fmaxf(m_run, mloc);
            float corr = __builtin_amdgcn_exp2f(m_run - mnew);
            #pragma unroll
            for (int st = 0; st < 4; ++st)
                #pragma unroll
                for (int r = 0; r < 4; ++r) {
                    float p = __builtin_amdgcn_exp2f(s[st][r] - mnew);
                    s[st][r] = p;
                    psum += p;
                }
            psum += __shfl_xor(psum, 16);
            psum += __shfl_xor(psum, 32);
            l_run = l_run * corr + psum;
            m_run = mnew;
            #pragma unroll
            for (int dt = 0; dt < 4; ++dt)
                #pragma unroll
                for (int r = 0; r < 4; ++r) o[dt][r] *= corr;
        }

        // stage P^T (16 q x 64 keys, bf16, swizzled) in wave-private LDS
        #pragma unroll
        for (int st = 0; st < 4; ++st) {
            int g8 = st * 2 + (lg >> 1);
            int byteoff = l15 * 128 + ((g8 ^ (l15 & 7)) * 16) + (lg & 1) * 8;
            short4v pv = {(short)f2bf(s[st][0]), (short)f2bf(s[st][1]),
                          (short)f2bf(s[st][2]), (short)f2bf(s[st][3])};
            *(short4v*)((char*)pb + byteoff) = pv;
        }

        // O^T += V^T . P^T  (64 d x 16 q)
        #pragma unroll
        for (int kk = 0; kk < 2; ++kk) {
            int grp = (kk * 4 + lg) ^ (l15 & 7);
            short8 bp = *(const short8*)&pb[l15 * 64 + grp * 8];
            #pragma unroll
            for (int dt = 0; dt < 4; ++dt) {
                int row = dt * 16 + l15;
                int ga = (kk * 4 + lg) ^ (row & 7);
                short8 av = *(const short8*)&vs[row * 64 + ga * 8];
                o[dt] = MFMA(av, bp, o[dt]);
            }
        }
        __syncthreads();
        cur ^= 1;
    }

    // epilogue: normalize, transpose via P buffer, coalesced 16B stores
    const float inv = 1.f / l_run;
    #pragma unroll
    for (int dt = 0; dt < 4; ++dt) {
        short4v pv = {(short)f2bf(o[dt][0] * inv), (short)f2bf(o[dt][1] * inv),
                      (short)f2bf(o[dt][2] * inv), (short)f2bf(o[dt][3] * inv)};
        *(short4v*)&pb[l15 * 64 + dt * 16 + lg * 4] = pv;
    }
    #pragma unroll
    for (int pass = 0; pass < 2; ++pass) {
        int idx = pass * 64 + lane;
        int row = idx >> 3, c8 = idx & 7;
        uint4 v = *(const uint4*)&pb[row * 64 + c8 * 8];
        *(uint4*)&outp[(size_t)(b * 1024 + q0 + wv * 16 + row) * 768 + h * 64 + c8 * 8] = v;
    }
}

// ---------------------------------------------------------------------------
extern "C" void kernel_launch(void* const* d_in, const int* in_sizes, int n_in,
                              void* d_out, int out_size, void* d_ws, size_t ws_size,
                              hipStream_t stream) {
    const float* x = (const float*)d_in[0];
    const float* w_qkv = (const float*)d_in[1];
    const float* b_qkv = (const float*)d_in[2];
    const float* w_proj = (const float*)d_in[3];
    const float* b_proj = (const float*)d_in[4];
    float* outp = (float*)d_out;

    char* ws = (char*)d_ws;
    ushort_t* x_bf = (ushort_t*)ws;   ws += (size_t)4096 * 768 * 2;
    ushort_t* wqT = (ushort_t*)ws;    ws += (size_t)2304 * 768 * 2;
    ushort_t* wpT = (ushort_t*)ws;    ws += (size_t)768 * 768 * 2;
    float* bq_p = (float*)ws;         ws += (size_t)2304 * 4;
    ushort_t* qkv_bf = (ushort_t*)ws; ws += (size_t)4096 * 2304 * 2;
    ushort_t* Vt = (ushort_t*)ws;     ws += (size_t)48 * 64 * 1024 * 2;
    ushort_t* aout = (ushort_t*)ws;

    // 1/sqrt(768) * log2(e): attn uses exp2
    const float scale = 0.036084391824351615f * 1.4426950408889634f;

    prep<<<2121, 256, 0, stream>>>(x, x_bf, w_qkv, wqT, w_proj, wpT,
                                   b_qkv, bq_p, scale);

    gemm_mfma<1, 128><<<dim3(18, 32), 256, 0, stream>>>(
        x_bf, wqT, bq_p, qkv_bf, Vt, 4096, 2304, 768);

    attn_mfma<<<dim3(16, 48), 256, 0, stream>>>(qkv_bf, Vt, aout);

    gemm_mfma<0, 64><<<dim3(12, 32), 256, 0, stream>>>(
        aout, wpT, b_proj, outp, nullptr, 4096, 768, 768);
}